// Round 16
// baseline (141.149 us; speedup 1.0000x reference)
//
#include <hip/hip_runtime.h>

#define NT    256                 // 4 waves per block
#define NWV   4
#define C     32                  // elements per lane per array
#define WIN   (NWV * 64 * C)      // 8192-float block window
#define VALID (WIN - 1024)        // 7168 valid outputs per block
#define WREG  (64 * C)            // 2048 words per wave transpose region

// tb: 8192 floats (32 KB), multi-purposed:
//   phase-A head halos overlaid at [0,256) (tb otherwise untouched in phase A)
//   wave-LOCAL transpose scratch [wv*2048,+2048)
//   phase-B halo regions (words), sized NWV*2*M*64, consecutive-layer disjoint:
//     R16:[0,512) R32:[512,1024) M1:[0,512) M2:[512,1536) M4:[1536,3584)
//     M8:[0,4096) with pre-barrier (overlaps M4 read region)
#define R16B 0
#define R32B 512
#define M1B  0
#define M2B  512
#define M4B  1536
#define M8B  0

#define KTS  2.885390081777927f   // 2*log2(e): h-state carried pre-scaled

// Swizzle: bits2-4 ^= (bits5-7 ^ bits8-9). Bijective; verified 0-conflict in R14.
__device__ __forceinline__ int tswz(int w) {
    return w ^ (((((w >> 5) & 7) ^ ((w >> 8) & 3))) << 2);
}

// phase-A halo word inside tb[0,256)
__device__ __forceinline__ int hAW(int I, int wv, int arr, int j) {
    return I * 64 + wv * 16 + arr * 8 + j;
}

__device__ __forceinline__ float fast_tanh_s(float s) {
    // s pre-scaled: s = 2*log2e*y ; tanh(y) = 1 - 2/(2^s+1). Saturates at +/-inf.
    float e = __builtin_amdgcn_exp2f(s);
    float r = __builtin_amdgcn_rcpf(e + 1.0f);
    return fmaf(-2.0f, r, 1.0f);
}

// ---------------- Phase A: contiguous layout, D in {1,2,4,8} ----------------
template<int D, int I>
__device__ __forceinline__ void layerA(float (&h)[C], float (&x)[C],
        const float* wh, const float* wx, int lane, int wv, float* tb)
{
    const float wh0 = wh[2*I],       wh1 = wh[2*I+1];
    const float wx0 = KTS*wx[2*I],   wx1 = KTS*wx[2*I+1];
    const int nw = (wv + 1) & (NWV - 1);

    if (lane == 0) {
        #pragma unroll
        for (int j = 0; j < D; ++j) {
            tb[hAW(I, wv, 0, j)] = h[j];
            tb[hAW(I, wv, 1, j)] = x[j];
        }
    }
    __syncthreads();

    float th[D], tx[D];
    #pragma unroll
    for (int j = 0; j < D; ++j) {
        th[j] = __shfl(h[j], (lane + 1) & 63, 64);
        tx[j] = __shfl(x[j], (lane + 1) & 63, 64);
        if (lane == 63) { th[j] = tb[hAW(I, nw, 0, j)]; tx[j] = tb[hAW(I, nw, 1, j)]; }
    }
    #pragma unroll
    for (int j = 0; j < C; ++j) {           // ascending j: h[j+D]/x[j+D] still old
        float hd = (j + D < C) ? h[j + D] : th[j + D - C];
        float xd = (j + D < C) ? x[j + D] : tx[j + D - C];
        float hn = fmaf(wh0, h[j], wh1 * hd);
        float s  = fmaf(wx0, x[j], hn);
        s        = fmaf(wx1, xd, s);
        h[j] = hn;
        x[j] = fast_tanh_s(s);
    }
}

// ------------- Phase B: stride-64 interleave, slot k = element lane+64k -------------

// D = R (16 or 32): select-before-shuffle (O(1) temps; verified R14).
template<int R, int BASE, int I>
__device__ __forceinline__ void layerBR(float (&hh)[C], float (&xx)[C],
        const float* wh, const float* wx, int lane, int wv, float* tb)
{
    const float wh0 = wh[2*I],     wh1 = wh[2*I+1];
    const float wx0 = KTS*wx[2*I], wx1 = KTS*wx[2*I+1];
    const int nw = (wv + 1) & (NWV - 1);

    tb[BASE + (wv*2+0)*64 + lane] = hh[0];     // publish slot 0 (all lanes)
    tb[BASE + (wv*2+1)*64 + lane] = xx[0];
    __syncthreads();

    const bool hi  = lane >= 64 - R;           // receives next wave's slot 0 at k=C-1
    const bool sel = lane >= R;                // this lane supplies slot k (else k+1)
    float hHal = 0.0f, xHal = 0.0f;
    if (hi) {
        hHal = tb[BASE + (nw*2+0)*64 + (lane - (64 - R))];
        xHal = tb[BASE + (nw*2+1)*64 + (lane - (64 - R))];
    }
    const int src = (lane + R) & 63;
    #pragma unroll
    for (int k = 0; k < C; ++k) {
        float vh = (k + 1 < C) ? (sel ? hh[k] : hh[k + 1]) : hh[k];
        float vx = (k + 1 < C) ? (sel ? xx[k] : xx[k + 1]) : xx[k];
        float hd = __shfl(vh, src, 64);
        float xd = __shfl(vx, src, 64);
        if (k == C - 1 && hi) { hd = hHal; xd = xHal; }
        float hn = fmaf(wh0, hh[k], wh1 * hd);
        float s  = fmaf(wx0, xx[k], hn);
        s        = fmaf(wx1, xd, s);
        hh[k] = hn;                            // ascending k: hh[k+1] read was old
        xx[k] = fast_tanh_s(s);
    }
}

// D = 64*M (M in {1,2,4,8}): pure slot shift; only slots >= C-M cross the wave.
template<int M, int BASE, bool PREBAR, int I>
__device__ __forceinline__ void layerBM(float (&hh)[C], float (&xx)[C],
        const float* wh, const float* wx, int lane, int wv, float* tb)
{
    const float wh0 = wh[2*I],     wh1 = wh[2*I+1];
    const float wx0 = KTS*wx[2*I], wx1 = KTS*wx[2*I+1];
    const int nw = (wv + 1) & (NWV - 1);

    if constexpr (PREBAR) __syncthreads();     // M=8 overwrites M4's read region

    #pragma unroll
    for (int s = 0; s < M; ++s) {              // publish head slots
        tb[BASE + ((wv*2+0)*M + s)*64 + lane] = hh[s];
        tb[BASE + ((wv*2+1)*M + s)*64 + lane] = xx[s];
    }
    __syncthreads();

    float nh[M], nx[M];
    #pragma unroll
    for (int s = 0; s < M; ++s) {              // next wave's head slots
        nh[s] = tb[BASE + ((nw*2+0)*M + s)*64 + lane];
        nx[s] = tb[BASE + ((nw*2+1)*M + s)*64 + lane];
    }
    #pragma unroll
    for (int k = 0; k < C; ++k) {              // ascending k: hh[k+M] still old
        float hd = (k + M < C) ? hh[k + M] : nh[k + M - C];
        float xd = (k + M < C) ? xx[k + M] : nx[k + M - C];
        float hn = fmaf(wh0, hh[k], wh1 * hd);
        float s  = fmaf(wx0, xx[k], hn);
        s        = fmaf(wx1, xd, s);
        hh[k] = hn;
        xx[k] = fast_tanh_s(s);
    }
}

// (256,2) -> VGPR cap 128 (R2-verified regime). Demand est ~110: state 64 + temps.
__global__ __launch_bounds__(NT, 2) void rawstack_w4c32(
    const float* __restrict__ hin, const float* __restrict__ xin,
    const float* __restrict__ wh,  const float* __restrict__ wx,
    float* __restrict__ out, int T, int Lout)
{
    __shared__ __align__(16) float tb[WIN];    // 32 KB

    const int lane = threadIdx.x & 63;
    const int wv   = __builtin_amdgcn_readfirstlane((int)(threadIdx.x >> 6));
    const int b    = blockIdx.y;
    const int W    = blockIdx.x * VALID;

    const float* hb = hin + (size_t)b * T;
    const float* xb = xin + (size_t)b * T;

    // ---- load contiguous chunks: 8 float4 per array (clamped; garbage in tail) ----
    float h[C], x[C];
    #pragma unroll
    for (int q = 0; q < C / 4; ++q) {
        int e = W + wv * WREG + lane * C + q * 4;
        e = (e > T - 4) ? (T - 4) : e;
        const float4 hv = *(const float4*)(hb + e);
        const float4 xv = *(const float4*)(xb + e);
        h[q*4+0] = KTS*hv.x; h[q*4+1] = KTS*hv.y; h[q*4+2] = KTS*hv.z; h[q*4+3] = KTS*hv.w;
        x[q*4+0] = xv.x;     x[q*4+1] = xv.y;     x[q*4+2] = xv.z;     x[q*4+3] = xv.w;
    }

    // ---- phase A: D = 1,2,4,8 (head halos live in tb[0,256)) ----
    layerA<1, 0>(h, x, wh, wx, lane, wv, tb);
    layerA<2, 1>(h, x, wh, wx, lane, wv, tb);
    layerA<4, 2>(h, x, wh, wx, lane, wv, tb);
    layerA<8, 3>(h, x, wh, wx, lane, wv, tb);

    __syncthreads();   // phase-A halo reads done before transpose overwrites tb

    // ---- transpose to stride-64 interleave: WAVE-LOCAL (own 2048-word region) ----
    float hh[C], xx[C];
    #pragma unroll
    for (int q = 0; q < C / 4; ++q) {
        const int w = tswz(wv * WREG + lane * C + q * 4);
        *(float4*)&tb[w] = make_float4(h[q*4+0], h[q*4+1], h[q*4+2], h[q*4+3]);
    }
    #pragma unroll
    for (int k = 0; k < C; ++k) hh[k] = tb[tswz(wv * WREG + lane + 64 * k)];
    #pragma unroll
    for (int q = 0; q < C / 4; ++q) {
        const int w = tswz(wv * WREG + lane * C + q * 4);
        *(float4*)&tb[w] = make_float4(x[q*4+0], x[q*4+1], x[q*4+2], x[q*4+3]);
    }
    #pragma unroll
    for (int k = 0; k < C; ++k) xx[k] = tb[tswz(wv * WREG + lane + 64 * k)];
    __syncthreads();   // cross-wave WAR: transpose reads done before halo pubs

    // ---- phase B: D=16,32 (select+shuffle), D=64..512 (slot shift) ----
    layerBR<16, R16B,        4>(hh, xx, wh, wx, lane, wv, tb);
    layerBR<32, R32B,        5>(hh, xx, wh, wx, lane, wv, tb);
    layerBM< 1, M1B,  false, 6>(hh, xx, wh, wx, lane, wv, tb);   // D=64
    layerBM< 2, M2B,  false, 7>(hh, xx, wh, wx, lane, wv, tb);   // D=128
    layerBM< 4, M4B,  false, 8>(hh, xx, wh, wx, lane, wv, tb);   // D=256
    layerBM< 8, M8B,  true,  9>(hh, xx, wh, wx, lane, wv, tb);   // D=512

    // ---- store (interleaved layout; idx<VALID guards wave 3's upper half) ----
    float* ob = out + (size_t)b * Lout;
    const int base = wv * WREG + lane;
    #pragma unroll
    for (int k = 0; k < C; ++k) {
        const int idx = base + 64 * k;
        const int col = W + idx;
        if (idx < VALID && col < Lout) ob[col] = xx[k];
    }
}

extern "C" void kernel_launch(void* const* d_in, const int* in_sizes, int n_in,
                              void* d_out, int out_size, void* d_ws, size_t ws_size,
                              hipStream_t stream) {
    const float* h  = (const float*)d_in[0];
    const float* x  = (const float*)d_in[1];
    const float* wh = (const float*)d_in[2];
    const float* wx = (const float*)d_in[3];
    float* out = (float*)d_out;

    const int B    = 64;
    const int T    = in_sizes[0] / B;   // 131072
    const int Lout = out_size / B;      // 130049

    const int blocksPerRow = (Lout + VALID - 1) / VALID;   // 19

    dim3 grid(blocksPerRow, B);
    rawstack_w4c32<<<grid, NT, 0, stream>>>(h, x, wh, wx, out, T, Lout);
}

// Round 17
// 53.599 us; speedup vs baseline: 2.6334x; 2.6334x over previous
//
#include <hip/hip_runtime.h>

#define NT    512                 // 8 waves per block
#define NWV   8
#define C     20                  // elements per lane per array (state 40 floats)
#define WIN   (NWV * 64 * C)      // 10240-float block window (40 KB)
#define VALID (WIN - 1024)        // 9216 valid outputs per block
#define WREG  (64 * C)            // 1280 words per wave transpose region

// tb: 10240 floats (40960 B exactly -> 4 blocks/CU), multi-purposed:
//   phase-A head halos overlaid at [0,512) (tb otherwise untouched in phase A)
//   wave-LOCAL transpose scratch [wv*1280,+1280)
//   phase-B halo regions (words, = NWV*2*M*64, independent of C; R11-verified map):
//     R16:[0,1024) R32:[1024,2048) M1:[0,1024) M2:[1024,3072) M4:[3072,7168)
//     M8:[0,8192) with pre-barrier (overlaps M4 read region)
#define R16B 0
#define R32B 1024
#define M1B  0
#define M2B  1024
#define M4B  3072
#define M8B  0

#define KTS  2.885390081777927f   // 2*log2(e): h-state carried pre-scaled

// Swizzle: bits2-4 ^= (bits5-7 ^ bits8-9). Bijective; flips only bits<5 so it
// stays inside any 32-word block (wave regions are 32-word aligned: 1280=40*32).
__device__ __forceinline__ int tswz(int w) {
    return w ^ (((((w >> 5) & 7) ^ ((w >> 8) & 3))) << 2);
}

// phase-A halo word inside tb[0,512)
__device__ __forceinline__ int hAW(int I, int wv, int arr, int j) {
    return I * 128 + wv * 16 + arr * 8 + j;
}

__device__ __forceinline__ float fast_tanh_s(float s) {
    // s pre-scaled: s = 2*log2e*y ; tanh(y) = 1 - 2/(2^s+1). Saturates at +/-inf.
    float e = __builtin_amdgcn_exp2f(s);
    float r = __builtin_amdgcn_rcpf(e + 1.0f);
    return fmaf(-2.0f, r, 1.0f);
}

// ---------------- Phase A: contiguous layout, D in {1,2,4,8} ----------------
// R11-verified flow; halos overlaid in tb[0,512) (R16-verified overlay).
template<int D, int I>
__device__ __forceinline__ void layerA(float (&h)[C], float (&x)[C],
        const float* wh, const float* wx, int lane, int wv, float* tb)
{
    const float wh0 = wh[2*I],       wh1 = wh[2*I+1];
    const float wx0 = KTS*wx[2*I],   wx1 = KTS*wx[2*I+1];
    const int nw = (wv + 1) & (NWV - 1);

    if (lane == 0) {
        #pragma unroll
        for (int j = 0; j < D; ++j) {
            tb[hAW(I, wv, 0, j)] = h[j];
            tb[hAW(I, wv, 1, j)] = x[j];
        }
    }
    __syncthreads();

    float th[D], tx[D];
    #pragma unroll
    for (int j = 0; j < D; ++j) {
        th[j] = __shfl(h[j], (lane + 1) & 63, 64);
        tx[j] = __shfl(x[j], (lane + 1) & 63, 64);
        if (lane == 63) { th[j] = tb[hAW(I, nw, 0, j)]; tx[j] = tb[hAW(I, nw, 1, j)]; }
    }
    #pragma unroll
    for (int j = 0; j < C; ++j) {           // ascending j: h[j+D]/x[j+D] still old
        float hd = (j + D < C) ? h[j + D] : th[j + D - C];
        float xd = (j + D < C) ? x[j + D] : tx[j + D - C];
        float hn = fmaf(wh0, h[j], wh1 * hd);
        float s  = fmaf(wx0, x[j], hn);
        s        = fmaf(wx1, xd, s);
        h[j] = hn;
        x[j] = fast_tanh_s(s);
    }
}

// ------------- Phase B: stride-64 interleave, slot k = element lane+64k -------------

// D = R (16 or 32): R11-verified shuffle+select with fh[C+1] staging.
template<int R, int BASE, int I>
__device__ __forceinline__ void layerBR(float (&hh)[C], float (&xx)[C],
        const float* wh, const float* wx, int lane, int wv, float* tb)
{
    const float wh0 = wh[2*I],     wh1 = wh[2*I+1];
    const float wx0 = KTS*wx[2*I], wx1 = KTS*wx[2*I+1];
    const int nw = (wv + 1) & (NWV - 1);

    tb[BASE + (wv*2+0)*64 + lane] = hh[0];     // publish slot 0 (all lanes)
    tb[BASE + (wv*2+1)*64 + lane] = xx[0];
    __syncthreads();

    float fh[C + 1], fx[C + 1];
    #pragma unroll
    for (int k = 0; k < C; ++k) {
        fh[k] = __shfl(hh[k], (lane + R) & 63, 64);
        fx[k] = __shfl(xx[k], (lane + R) & 63, 64);
    }
    fh[C] = 0.0f; fx[C] = 0.0f;
    if (lane >= 64 - R) {                      // slot-C = next wave's slot 0
        fh[C] = tb[BASE + (nw*2+0)*64 + (lane - (64 - R))];
        fx[C] = tb[BASE + (nw*2+1)*64 + (lane - (64 - R))];
    }
    const bool lo = lane < 64 - R;
    #pragma unroll
    for (int k = 0; k < C; ++k) {
        float hd = lo ? fh[k] : fh[k + 1];
        float xd = lo ? fx[k] : fx[k + 1];
        float hn = fmaf(wh0, hh[k], wh1 * hd);
        float s  = fmaf(wx0, xx[k], hn);
        s        = fmaf(wx1, xd, s);
        hh[k] = hn;
        xx[k] = fast_tanh_s(s);
    }
}

// D = 64*M (M in {1,2,4,8}): pure slot shift; only slots >= C-M cross the wave.
template<int M, int BASE, bool PREBAR, int I>
__device__ __forceinline__ void layerBM(float (&hh)[C], float (&xx)[C],
        const float* wh, const float* wx, int lane, int wv, float* tb)
{
    const float wh0 = wh[2*I],     wh1 = wh[2*I+1];
    const float wx0 = KTS*wx[2*I], wx1 = KTS*wx[2*I+1];
    const int nw = (wv + 1) & (NWV - 1);

    if constexpr (PREBAR) __syncthreads();     // M=8 overwrites M4's read region

    #pragma unroll
    for (int s = 0; s < M; ++s) {              // publish head slots
        tb[BASE + ((wv*2+0)*M + s)*64 + lane] = hh[s];
        tb[BASE + ((wv*2+1)*M + s)*64 + lane] = xx[s];
    }
    __syncthreads();

    float nh[M], nx[M];
    #pragma unroll
    for (int s = 0; s < M; ++s) {              // next wave's head slots
        nh[s] = tb[BASE + ((nw*2+0)*M + s)*64 + lane];
        nx[s] = tb[BASE + ((nw*2+1)*M + s)*64 + lane];
    }
    #pragma unroll
    for (int k = 0; k < C; ++k) {              // ascending k: hh[k+M] still old
        float hd = (k + M < C) ? hh[k + M] : nh[k + M - C];
        float xd = (k + M < C) ? xx[k + M] : nx[k + M - C];
        float hn = fmaf(wh0, hh[k], wh1 * hd);
        float s  = fmaf(wx0, xx[k], hn);
        s        = fmaf(wx1, xd, s);
        hh[k] = hn;
        xx[k] = fast_tanh_s(s);
    }
}

// (512,4) -> VGPR cap 64, the R10/R11-VERIFIED no-spill regime (natural ~40 at
// C=16; ~48-56 expected at C=20). Grid 960 blocks <= 1024 residency slots
// (4 blocks/CU x 256 CU) -> single generation, no straggler tail.
__global__ __launch_bounds__(NT, 4) void rawstack_c20(
    const float* __restrict__ hin, const float* __restrict__ xin,
    const float* __restrict__ wh,  const float* __restrict__ wx,
    float* __restrict__ out, int T, int Lout)
{
    __shared__ __align__(16) float tb[WIN];    // 40960 B exactly

    const int lane = threadIdx.x & 63;
    const int wv   = __builtin_amdgcn_readfirstlane((int)(threadIdx.x >> 6));
    const int b    = blockIdx.y;
    const int W    = blockIdx.x * VALID;

    const float* hb = hin + (size_t)b * T;
    const float* xb = xin + (size_t)b * T;

    // ---- load contiguous chunks: 5 float4 per array (clamped at row end;
    //      clamp garbage propagates back <=1023 -> lands past the 1024 needed prefix) ----
    float h[C], x[C];
    #pragma unroll
    for (int q = 0; q < C / 4; ++q) {
        int e = W + wv * WREG + lane * C + q * 4;
        e = (e > T - 4) ? (T - 4) : e;
        const float4 hv = *(const float4*)(hb + e);
        const float4 xv = *(const float4*)(xb + e);
        h[q*4+0] = KTS*hv.x; h[q*4+1] = KTS*hv.y; h[q*4+2] = KTS*hv.z; h[q*4+3] = KTS*hv.w;
        x[q*4+0] = xv.x;     x[q*4+1] = xv.y;     x[q*4+2] = xv.z;     x[q*4+3] = xv.w;
    }

    // ---- phase A: D = 1,2,4,8 (head halos live in tb[0,512)) ----
    layerA<1, 0>(h, x, wh, wx, lane, wv, tb);
    layerA<2, 1>(h, x, wh, wx, lane, wv, tb);
    layerA<4, 2>(h, x, wh, wx, lane, wv, tb);
    layerA<8, 3>(h, x, wh, wx, lane, wv, tb);

    __syncthreads();   // phase-A halo reads done before transpose overwrites tb

    // ---- transpose to stride-64 interleave: WAVE-LOCAL (own 1280-word region) ----
    float hh[C], xx[C];
    #pragma unroll
    for (int q = 0; q < C / 4; ++q) {
        const int w = tswz(wv * WREG + lane * C + q * 4);
        *(float4*)&tb[w] = make_float4(h[q*4+0], h[q*4+1], h[q*4+2], h[q*4+3]);
    }
    #pragma unroll
    for (int k = 0; k < C; ++k) hh[k] = tb[tswz(wv * WREG + lane + 64 * k)];
    #pragma unroll
    for (int q = 0; q < C / 4; ++q) {
        const int w = tswz(wv * WREG + lane * C + q * 4);
        *(float4*)&tb[w] = make_float4(x[q*4+0], x[q*4+1], x[q*4+2], x[q*4+3]);
    }
    #pragma unroll
    for (int k = 0; k < C; ++k) xx[k] = tb[tswz(wv * WREG + lane + 64 * k)];
    __syncthreads();   // cross-wave WAR: transpose reads done before halo pubs

    // ---- phase B: D=16,32 (shuffle+select), D=64..512 (slot shift) ----
    layerBR<16, R16B,        4>(hh, xx, wh, wx, lane, wv, tb);
    layerBR<32, R32B,        5>(hh, xx, wh, wx, lane, wv, tb);
    layerBM< 1, M1B,  false, 6>(hh, xx, wh, wx, lane, wv, tb);   // D=64
    layerBM< 2, M2B,  false, 7>(hh, xx, wh, wx, lane, wv, tb);   // D=128
    layerBM< 4, M4B,  false, 8>(hh, xx, wh, wx, lane, wv, tb);   // D=256
    layerBM< 8, M8B,  true,  9>(hh, xx, wh, wx, lane, wv, tb);   // D=512

    // ---- store (interleaved layout; idx<VALID guards the invalid tail) ----
    float* ob = out + (size_t)b * Lout;
    const int base = wv * WREG + lane;
    #pragma unroll
    for (int k = 0; k < C; ++k) {
        const int idx = base + 64 * k;
        const int col = W + idx;
        if (idx < VALID && col < Lout) ob[col] = xx[k];
    }
}

extern "C" void kernel_launch(void* const* d_in, const int* in_sizes, int n_in,
                              void* d_out, int out_size, void* d_ws, size_t ws_size,
                              hipStream_t stream) {
    const float* h  = (const float*)d_in[0];
    const float* x  = (const float*)d_in[1];
    const float* wh = (const float*)d_in[2];
    const float* wx = (const float*)d_in[3];
    float* out = (float*)d_out;

    const int B    = 64;
    const int T    = in_sizes[0] / B;   // 131072
    const int Lout = out_size / B;      // 130049

    const int blocksPerRow = (Lout + VALID - 1) / VALID;   // 15 -> 960 blocks total

    dim3 grid(blocksPerRow, B);
    rawstack_c20<<<grid, NT, 0, stream>>>(h, x, wh, wx, out, T, Lout);
}

// Round 18
// 47.941 us; speedup vs baseline: 2.9442x; 1.1180x over previous
//
#include <hip/hip_runtime.h>

#define NT    512                // 8 waves per block
#define NWV   8
#define WIN   8192               // block window (floats)
#define VALID 7168               // valid outputs per block (halo 1024)
#define C     16                 // elements per lane per array

// tb halo regions (words), consecutive-layer disjoint (verified R11):
#define R16B 0
#define R32B 1024
#define M1B  0
#define M2B  1024
#define M4B  3072
#define M8B  0

#define KTS  2.885390081777927f  // 2*log2(e): h-state carried pre-scaled

// XOR-swizzle for the transpose pattern (bits 2..4 ^= bits 5..7); wave-local.
__device__ __forceinline__ int tswz(int w) { return w ^ (((w >> 5) & 7) << 2); }

__device__ __forceinline__ float fast_tanh_s(float s) {
    // s pre-scaled: s = 2*log2e*y ; tanh(y) = 1 - 2/(2^s+1). Saturates at +/-inf.
    float e = __builtin_amdgcn_exp2f(s);
    float r = __builtin_amdgcn_rcpf(e + 1.0f);
    return fmaf(-2.0f, r, 1.0f);
}

// ---------------- Phase A: contiguous layout, D in {1,2,4,8} ----------------
template<int D, int I>
__device__ __forceinline__ void layerA(float (&h)[C], float (&x)[C],
        const float* wh, const float* wx, int lane, int wv,
        float (*hA)[NWV][2][8])
{
    const float wh0 = wh[2*I],       wh1 = wh[2*I+1];
    const float wx0 = KTS*wx[2*I],   wx1 = KTS*wx[2*I+1];
    const int nw = (wv + 1) & (NWV - 1);

    if (lane == 0) {
        #pragma unroll
        for (int j = 0; j < D; ++j) { hA[I][wv][0][j] = h[j]; hA[I][wv][1][j] = x[j]; }
    }
    __syncthreads();

    float th[D], tx[D];
    #pragma unroll
    for (int j = 0; j < D; ++j) {
        th[j] = __shfl(h[j], (lane + 1) & 63, 64);
        tx[j] = __shfl(x[j], (lane + 1) & 63, 64);
        if (lane == 63) { th[j] = hA[I][nw][0][j]; tx[j] = hA[I][nw][1][j]; }
    }
    #pragma unroll
    for (int j = 0; j < C; ++j) {           // ascending j: h[j+D]/x[j+D] still old
        float hd = (j + D < C) ? h[j + D] : th[j + D - C];
        float xd = (j + D < C) ? x[j + D] : tx[j + D - C];
        float hn = fmaf(wh0, h[j], wh1 * hd);
        float s  = fmaf(wx0, x[j], hn);
        s        = fmaf(wx1, xd, s);
        h[j] = hn;
        x[j] = fast_tanh_s(s);
    }
}

// ------------- Phase B: stride-64 interleave, slot k = element lane+64k -------------

// D = R (16 or 32): j+R -> lane (l+R)&63, slot k (+1 for high lanes).
template<int R, int BASE, int I>
__device__ __forceinline__ void layerBR(float (&hh)[C], float (&xx)[C],
        const float* wh, const float* wx, int lane, int wv, float* tb)
{
    const float wh0 = wh[2*I],     wh1 = wh[2*I+1];
    const float wx0 = KTS*wx[2*I], wx1 = KTS*wx[2*I+1];
    const int nw = (wv + 1) & (NWV - 1);

    tb[BASE + (wv*2+0)*64 + lane] = hh[0];     // publish slot 0 (all lanes)
    tb[BASE + (wv*2+1)*64 + lane] = xx[0];
    __syncthreads();

    float fh[C + 1], fx[C + 1];
    #pragma unroll
    for (int k = 0; k < C; ++k) {
        fh[k] = __shfl(hh[k], (lane + R) & 63, 64);
        fx[k] = __shfl(xx[k], (lane + R) & 63, 64);
    }
    fh[C] = 0.0f; fx[C] = 0.0f;
    if (lane >= 64 - R) {                      // slot-16 = next wave's slot 0
        fh[C] = tb[BASE + (nw*2+0)*64 + (lane - (64 - R))];
        fx[C] = tb[BASE + (nw*2+1)*64 + (lane - (64 - R))];
    }
    const bool lo = lane < 64 - R;
    #pragma unroll
    for (int k = 0; k < C; ++k) {
        float hd = lo ? fh[k] : fh[k + 1];
        float xd = lo ? fx[k] : fx[k + 1];
        float hn = fmaf(wh0, hh[k], wh1 * hd);
        float s  = fmaf(wx0, xx[k], hn);
        s        = fmaf(wx1, xd, s);
        hh[k] = hn;
        xx[k] = fast_tanh_s(s);
    }
}

// D = 64*M (M in {1,2,4,8}): pure slot shift; only slots >= 16-M cross the wave.
template<int M, int BASE, bool PREBAR, int I>
__device__ __forceinline__ void layerBM(float (&hh)[C], float (&xx)[C],
        const float* wh, const float* wx, int lane, int wv, float* tb)
{
    const float wh0 = wh[2*I],     wh1 = wh[2*I+1];
    const float wx0 = KTS*wx[2*I], wx1 = KTS*wx[2*I+1];
    const int nw = (wv + 1) & (NWV - 1);

    if constexpr (PREBAR) __syncthreads();     // M=8 overwrites prior read regions

    #pragma unroll
    for (int s = 0; s < M; ++s) {              // publish head slots
        tb[BASE + ((wv*2+0)*M + s)*64 + lane] = hh[s];
        tb[BASE + ((wv*2+1)*M + s)*64 + lane] = xx[s];
    }
    __syncthreads();

    float nh[M], nx[M];
    #pragma unroll
    for (int s = 0; s < M; ++s) {              // next wave's head slots
        nh[s] = tb[BASE + ((nw*2+0)*M + s)*64 + lane];
        nx[s] = tb[BASE + ((nw*2+1)*M + s)*64 + lane];
    }
    #pragma unroll
    for (int k = 0; k < C; ++k) {              // ascending k: hh[k+M] still old
        float hd = (k + M < C) ? hh[k + M] : nh[k + M - C];
        float xd = (k + M < C) ? xx[k + M] : nx[k + M - C];
        float hn = fmaf(wh0, hh[k], wh1 * hd);
        float s  = fmaf(wx0, xx[k], hn);
        s        = fmaf(wx1, xd, s);
        hh[k] = hn;
        xx[k] = fast_tanh_s(s);
    }
}

// launch_bounds arg2: empirical VGPR cap = 256/arg2. arg2=4 -> cap 64;
// natural usage ~40 (R10/R11 verified, no spill); residency 4x8=32 waves/CU.
__global__ __launch_bounds__(NT, 4) void rawstack_w8c(
    const float* __restrict__ hin, const float* __restrict__ xin,
    const float* __restrict__ wh,  const float* __restrict__ wx,
    float* __restrict__ out, int T, int Lout)
{
    __shared__ __align__(16) float tb[WIN];    // 32 KB transpose/halo buffer
    __shared__ float hA[4][NWV][2][8];         // 2 KB phase-A head halos

    const int lane = threadIdx.x & 63;
    // wave-uniform -> force into SGPR so all tb/hA addressing is scalar
    const int wv   = __builtin_amdgcn_readfirstlane((int)(threadIdx.x >> 6));
    const int b    = blockIdx.y;
    const int W    = blockIdx.x * VALID;

    const float* hb = hin + (size_t)b * T;
    const float* xb = xin + (size_t)b * T;

    // ---- load contiguous chunks (clamped; garbage stays in invalid tail) ----
    // h is carried pre-scaled by KTS (linear path; output is x, never unscaled h)
    float h[C], x[C];
    #pragma unroll
    for (int q = 0; q < C / 4; ++q) {
        int e = W + wv * 1024 + lane * C + q * 4;
        e = (e > T - 4) ? (T - 4) : e;
        const float4 hv = *(const float4*)(hb + e);
        const float4 xv = *(const float4*)(xb + e);
        h[q*4+0] = KTS*hv.x; h[q*4+1] = KTS*hv.y; h[q*4+2] = KTS*hv.z; h[q*4+3] = KTS*hv.w;
        x[q*4+0] = xv.x;     x[q*4+1] = xv.y;     x[q*4+2] = xv.z;     x[q*4+3] = xv.w;
    }

    // ---- phase A: D = 1,2,4,8 ----
    layerA<1, 0>(h, x, wh, wx, lane, wv, hA);
    layerA<2, 1>(h, x, wh, wx, lane, wv, hA);
    layerA<4, 2>(h, x, wh, wx, lane, wv, hA);
    layerA<8, 3>(h, x, wh, wx, lane, wv, hA);

    // ---- transpose to stride-64 interleave: WAVE-LOCAL (own quarter only),
    //      no __syncthreads inside; same-wave LDS ordering is hardware-guaranteed.
    float hh[C], xx[C];
    #pragma unroll
    for (int q = 0; q < C / 4; ++q) {
        const int w = tswz(wv * 1024 + lane * C + q * 4);
        *(float4*)&tb[w] = make_float4(h[q*4+0], h[q*4+1], h[q*4+2], h[q*4+3]);
    }
    #pragma unroll
    for (int k = 0; k < C; ++k) hh[k] = tb[tswz(wv * 1024 + lane + 64 * k)];
    #pragma unroll
    for (int q = 0; q < C / 4; ++q) {
        const int w = tswz(wv * 1024 + lane * C + q * 4);
        *(float4*)&tb[w] = make_float4(x[q*4+0], x[q*4+1], x[q*4+2], x[q*4+3]);
    }
    #pragma unroll
    for (int k = 0; k < C; ++k) xx[k] = tb[tswz(wv * 1024 + lane + 64 * k)];
    __syncthreads();   // cross-wave WAR: all transpose reads done before halo pubs

    // ---- phase B: D = 16,32 (shuffle+select), D = 64..512 (slot shift) ----
    layerBR<16, R16B,        4>(hh, xx, wh, wx, lane, wv, tb);
    layerBR<32, R32B,        5>(hh, xx, wh, wx, lane, wv, tb);
    layerBM< 1, M1B,  false, 6>(hh, xx, wh, wx, lane, wv, tb);   // D=64
    layerBM< 2, M2B,  false, 7>(hh, xx, wh, wx, lane, wv, tb);   // D=128
    layerBM< 4, M4B,  false, 8>(hh, xx, wh, wx, lane, wv, tb);   // D=256
    layerBM< 8, M8B,  true,  9>(hh, xx, wh, wx, lane, wv, tb);   // D=512, full tb

    // ---- store (interleaved layout; waves 0..6 hold the 7168 valid outputs) ----
    if (wv < 7) {
        float* ob = out + (size_t)b * Lout;
        const int base = W + wv * 1024 + lane;
        #pragma unroll
        for (int k = 0; k < C; ++k) {
            const int col = base + 64 * k;
            if (col < Lout) ob[col] = xx[k];
        }
    }
}

extern "C" void kernel_launch(void* const* d_in, const int* in_sizes, int n_in,
                              void* d_out, int out_size, void* d_ws, size_t ws_size,
                              hipStream_t stream) {
    const float* h  = (const float*)d_in[0];
    const float* x  = (const float*)d_in[1];
    const float* wh = (const float*)d_in[2];
    const float* wx = (const float*)d_in[3];
    float* out = (float*)d_out;

    const int B    = 64;
    const int T    = in_sizes[0] / B;   // 131072
    const int Lout = out_size / B;      // 130049

    const int blocksPerRow = (Lout + VALID - 1) / VALID;   // 19

    dim3 grid(blocksPerRow, B);
    rawstack_w8c<<<grid, NT, 0, stream>>>(h, x, wh, wx, out, T, Lout);
}